// Round 20
// baseline (212.386 us; speedup 1.0000x reference)
//
#include <hip/hip_runtime.h>
#include <math.h>

#define NHEAD 8
#define DD 128
#define HIDD 512
#define NB 768   // persistent feat blocks inside fused kernel A

typedef _Float16 half8 __attribute__((ext_vector_type(8)));
typedef _Float16 half4 __attribute__((ext_vector_type(4)));
typedef float floatx4 __attribute__((ext_vector_type(4)));

__device__ __forceinline__ int swz256(int row, int bytecol) {  // 256B rows (128 f16)
  return row * 256 + (bytecol ^ ((row & 15) << 4));
}

// ---------------- K0: pack WP only (needed immediately by featcount) ----------------
__global__ __launch_bounds__(256) void pack_kernel(
    const float* __restrict__ W, _Float16* __restrict__ WP)
{
  int i = blockIdx.x * 256 + threadIdx.x;
  if (i < 4 * 128 * 4 * 8) {   // WP <- W[128][128]
    int ii = i & 7, l4 = (i >> 3) & 3, col = (i >> 5) & 127, kc = i >> 12;
    WP[i] = (_Float16)W[(kc * 32 + l4 * 8 + ii) * DD + col];
  }
}

// ---------------- KA: fused feat+elr (persistent MFMA) | count | pack W1TP/W2P ----------------
__global__ __launch_bounds__(256) void featcount_kernel(
    const float* __restrict__ x, const _Float16* __restrict__ WP,
    const float* __restrict__ attn_l, const float* __restrict__ attn_r,
    _Float16* __restrict__ feat16, float* __restrict__ el, float* __restrict__ er,
    int N, int T,
    const int* __restrict__ dst, int* __restrict__ counts,
    int* __restrict__ rank, int E,
    const float* __restrict__ W1, const float* __restrict__ W2,
    _Float16* __restrict__ W1TP, _Float16* __restrict__ W2P, int countB)
{
  if (blockIdx.x >= NB + countB) {   // ---- pack W1TP / W2P path ----
    int i = (blockIdx.x - NB - countB) * 256 + threadIdx.x;   // 0..65535
    {
      int ii = i & 7, e = (i >> 3) & 63, tile = i >> 9;
      int l4 = e >> 4, l15 = e & 15, hb = tile >> 2, kc = tile & 3;
      W1TP[i] = (_Float16)W1[(size_t)(kc * 32 + l4 * 8 + ii) * HIDD + hb * 16 + l15];
    }
    {
      int ii = i & 7, e = (i >> 3) & 63, tile = i >> 9;
      int l4 = e >> 4, l15 = e & 15, c = tile >> 3, cb = tile & 7;
      int hidden = (ii < 4) ? (2 * c) * 16 + 4 * l4 + ii
                            : (2 * c + 1) * 16 + 4 * l4 + (ii - 4);
      W2P[i] = (_Float16)W2[(size_t)hidden * DD + cb * 16 + l15];
    }
    return;
  }
  if (blockIdx.x >= NB) {   // ---- count path ----
    int e = (blockIdx.x - NB) * 256 + threadIdx.x;
    if (e < E) rank[e] = atomicAdd(&counts[dst[e]], 1);
    return;
  }
  // ---- feat path ----
  __shared__ char xs[32 * 256];   // 8KB f16 swizzled A-tile
  const int tid = threadIdx.x;
  const int wv = tid >> 6, lane = tid & 63;
  const int l15 = lane & 15, l4 = lane >> 4;
  const int row = tid >> 3, seg = tid & 7;

  const float al0 = attn_l[wv * 32 + l15], al1 = attn_l[wv * 32 + 16 + l15];
  const float ar0 = attn_r[wv * 32 + l15], ar1 = attn_r[wv * 32 + 16 + l15];

  int t = blockIdx.x;
  float4 pre[4];
  {
    const int n = t * 32 + row;
    const bool ok = (t < T) && (n < N);
    const float4* sp = (const float4*)(x + (size_t)n * DD + seg * 16);
    const float4 z = make_float4(0.f, 0.f, 0.f, 0.f);
    #pragma unroll
    for (int c = 0; c < 4; ++c) pre[c] = ok ? sp[c] : z;
  }

  for (; t < T; t += NB) {
    const int n0 = t * 32;
    {  // stage: convert f32->f16 once, 2x 16B swizzled stores
      half8 h0, h1;
      #pragma unroll
      for (int c = 0; c < 4; ++c) {
        float4 v = pre[c];
        if (c < 2) {
          h0[c * 4 + 0] = (_Float16)v.x; h0[c * 4 + 1] = (_Float16)v.y;
          h0[c * 4 + 2] = (_Float16)v.z; h0[c * 4 + 3] = (_Float16)v.w;
        } else {
          h1[(c - 2) * 4 + 0] = (_Float16)v.x; h1[(c - 2) * 4 + 1] = (_Float16)v.y;
          h1[(c - 2) * 4 + 2] = (_Float16)v.z; h1[(c - 2) * 4 + 3] = (_Float16)v.w;
        }
      }
      *(half8*)(xs + swz256(row, seg * 32)) = h0;
      *(half8*)(xs + swz256(row, seg * 32 + 16)) = h1;
    }
    __syncthreads();

    floatx4 acc[2][2];
    #pragma unroll
    for (int mf = 0; mf < 2; ++mf) { acc[mf][0] = (floatx4)0.f; acc[mf][1] = (floatx4)0.f; }

    #pragma unroll
    for (int kc = 0; kc < 4; ++kc) {
      half8 b0 = *(const half8*)(WP + ((kc * 128 + wv * 32 + l15) * 4 + l4) * 8);
      half8 b1 = *(const half8*)(WP + ((kc * 128 + wv * 32 + 16 + l15) * 4 + l4) * 8);
      #pragma unroll
      for (int mf = 0; mf < 2; ++mf) {
        half8 af = *(const half8*)(xs + swz256(mf * 16 + l15, kc * 64 + l4 * 16));
        acc[mf][0] = __builtin_amdgcn_mfma_f32_16x16x32_f16(af, b0, acc[mf][0], 0, 0, 0);
        acc[mf][1] = __builtin_amdgcn_mfma_f32_16x16x32_f16(af, b1, acc[mf][1], 0, 0, 0);
      }
    }

    {  // prefetch next tile
      const int tn = t + NB;
      const int n = tn * 32 + row;
      const bool ok = (tn < T) && (n < N);
      const float4* sp = (const float4*)(x + (size_t)n * DD + seg * 16);
      const float4 z = make_float4(0.f, 0.f, 0.f, 0.f);
      #pragma unroll
      for (int c = 0; c < 4; ++c) pre[c] = ok ? sp[c] : z;
    }

    // epilogue: store feat16 + el/er via 16-lane shfl reduction
    #pragma unroll
    for (int mf = 0; mf < 2; ++mf) {
      #pragma unroll
      for (int r = 0; r < 4; ++r) {
        const int rown = n0 + mf * 16 + l4 * 4 + r;
        float v0 = acc[mf][0][r], v1 = acc[mf][1][r];
        float e0l = v0 * al0, e0r = v0 * ar0;
        float e1l = v1 * al1, e1r = v1 * ar1;
        #pragma unroll
        for (int d = 1; d < 16; d <<= 1) {
          e0l += __shfl_xor(e0l, d, 64); e0r += __shfl_xor(e0r, d, 64);
          e1l += __shfl_xor(e1l, d, 64); e1r += __shfl_xor(e1r, d, 64);
        }
        if (rown < N) {
          feat16[(size_t)rown * DD + wv * 32 + l15] = (_Float16)v0;
          feat16[(size_t)rown * DD + wv * 32 + 16 + l15] = (_Float16)v1;
          if (l15 == 0) {
            el[rown * NHEAD + wv * 2] = e0l;     er[rown * NHEAD + wv * 2] = e0r;
            el[rown * NHEAD + wv * 2 + 1] = e1l; er[rown * NHEAD + wv * 2 + 1] = e1r;
          }
        }
      }
    }
    __syncthreads();
  }
}

// ---------------- K3a/K3b: two-level exclusive scan ----------------
__global__ __launch_bounds__(256) void scan1_kernel(const int* __restrict__ counts,
                                                    int* __restrict__ offsets,
                                                    int* __restrict__ btot)
{
  __shared__ int wsum[4];
  const int lane = threadIdx.x & 63;
  const int wid = threadIdx.x >> 6;
  int4 c = *(const int4*)(counts + blockIdx.x * 1024 + threadIdx.x * 4);
  int q = c.x + c.y + c.z + c.w;
  int incl = q;
  #pragma unroll
  for (int d = 1; d < 64; d <<= 1) {
    int t = __shfl_up(incl, d, 64);
    if (lane >= d) incl += t;
  }
  if (lane == 63) wsum[wid] = incl;
  __syncthreads();
  int wprefix = 0;
  for (int w = 0; w < wid; ++w) wprefix += wsum[w];
  int excl = wprefix + incl - q;
  int4 o;
  o.x = excl; o.y = excl + c.x; o.z = o.y + c.y; o.w = o.z + c.z;
  *(int4*)(offsets + blockIdx.x * 1024 + threadIdx.x * 4) = o;
  if (threadIdx.x == 0) btot[blockIdx.x] = wsum[0] + wsum[1] + wsum[2] + wsum[3];
}

__global__ __launch_bounds__(64) void scan2_kernel(const int* __restrict__ btot,
                                                   int* __restrict__ bof, int nchunk)
{
  const int t = threadIdx.x;
  const int K = (nchunk + 63) >> 6;
  const int base = t * K;
  int s = 0;
  for (int i = 0; i < K; ++i) if (base + i < nchunk) s += btot[base + i];
  int incl = s;
  #pragma unroll
  for (int d = 1; d < 64; d <<= 1) {
    int tt = __shfl_up(incl, d, 64);
    if (t >= d) incl += tt;
  }
  int run = incl - s;
  for (int i = 0; i < K; ++i) if (base + i < nchunk) { bof[base + i] = run; run += btot[base + i]; }
}

// ---------------- K4: bucket edges by dst ----------------
__global__ __launch_bounds__(256) void fill_kernel(const int* __restrict__ src,
                                                   const int* __restrict__ dst,
                                                   const int* __restrict__ offsets,
                                                   const int* __restrict__ bof,
                                                   const int* __restrict__ rank,
                                                   int* __restrict__ srcl, int E)
{
  int e = blockIdx.x * 256 + threadIdx.x;
  if (e < E) {
    int d = dst[e];
    srcl[offsets[d] + bof[d >> 10] + rank[e]] = src[e];
  }
}

// ---------------- K5: pair-split aggregate, fused el-gather, unroll x4 ----------------
__global__ __launch_bounds__(256) void agg_kernel(
    const _Float16* __restrict__ feat16, const float* __restrict__ el,
    const float* __restrict__ er, const int* __restrict__ offsets,
    const int* __restrict__ bof, const int* __restrict__ srcl,
    const float* __restrict__ bias, float* __restrict__ hout, int N)
{
  int gid = blockIdx.x * 256 + threadIdx.x;
  if (gid >= N * 16) return;
  const int n = gid >> 4;
  const int sub = gid & 15;
  const int hh = sub >> 1;
  const int half = sub & 1;
  const int o0 = offsets[n] + bof[n >> 10];
  const int o1 = offsets[n + 1] + bof[(n + 1) >> 10];
  const int cnt = o1 - o0;
  const int mid = o0 + ((cnt + 1) >> 1);
  int j = half ? mid : o0;
  const int je = half ? o1 : mid;
  const float er_nh = er[n * NHEAD + hh];

  float s = 0.f;
  float a[16];
  #pragma unroll
  for (int d = 0; d < 16; ++d) a[d] = 0.f;

  for (; j + 3 < je; j += 4) {
    const int s0 = srcl[j], s1 = srcl[j + 1], s2 = srcl[j + 2], s3 = srcl[j + 3];
    float e0 = el[s0 * NHEAD + hh] + er_nh;
    float e1 = el[s1 * NHEAD + hh] + er_nh;
    float e2 = el[s2 * NHEAD + hh] + er_nh;
    float e3 = el[s3 * NHEAD + hh] + er_nh;
    const half8* f0p = (const half8*)(feat16 + (size_t)s0 * DD + hh * 16);
    const half8* f1p = (const half8*)(feat16 + (size_t)s1 * DD + hh * 16);
    const half8* f2p = (const half8*)(feat16 + (size_t)s2 * DD + hh * 16);
    const half8* f3p = (const half8*)(feat16 + (size_t)s3 * DD + hh * 16);
    e0 = e0 > 0.f ? e0 : 0.2f * e0;
    e1 = e1 > 0.f ? e1 : 0.2f * e1;
    e2 = e2 > 0.f ? e2 : 0.2f * e2;
    e3 = e3 > 0.f ? e3 : 0.2f * e3;
    const float p0 = __expf(e0), p1 = __expf(e1), p2 = __expf(e2), p3 = __expf(e3);
    half8 f00 = f0p[0], f01 = f0p[1];
    half8 f10 = f1p[0], f11 = f1p[1];
    half8 f20 = f2p[0], f21 = f2p[1];
    half8 f30 = f3p[0], f31 = f3p[1];
    s += (p0 + p1) + (p2 + p3);
    #pragma unroll
    for (int d = 0; d < 8; ++d) {
      float t0 = fmaf(p0, (float)f00[d], fmaf(p1, (float)f10[d], a[d]));
      a[d] = fmaf(p2, (float)f20[d], fmaf(p3, (float)f30[d], t0));
      float t1 = fmaf(p0, (float)f01[d], fmaf(p1, (float)f11[d], a[d + 8]));
      a[d + 8] = fmaf(p2, (float)f21[d], fmaf(p3, (float)f31[d], t1));
    }
  }
  for (; j < je; ++j) {
    const int s0 = srcl[j];
    float e0 = el[s0 * NHEAD + hh] + er_nh;
    e0 = e0 > 0.f ? e0 : 0.2f * e0;
    const float p0 = __expf(e0);
    const half8* f0p = (const half8*)(feat16 + (size_t)s0 * DD + hh * 16);
    half8 f00 = f0p[0], f01 = f0p[1];
    s += p0;
    #pragma unroll
    for (int d = 0; d < 8; ++d) {
      a[d]     = fmaf(p0, (float)f00[d], a[d]);
      a[d + 8] = fmaf(p0, (float)f01[d], a[d + 8]);
    }
  }

  s += __shfl_xor(s, 1, 64);
  #pragma unroll
  for (int d = 0; d < 16; ++d) a[d] += __shfl_xor(a[d], 1, 64);

  const float inv = (cnt > 0) ? 1.f / s : 0.f;
  const int cbase = hh * 16 + half * 8;
  float* op = hout + (size_t)n * DD + cbase;
  const float* bp = bias + cbase;
  const int abase = half * 8;
  float4 o0v, o1v;
  o0v.x = fmaf(a[abase + 0], inv, bp[0]);
  o0v.y = fmaf(a[abase + 1], inv, bp[1]);
  o0v.z = fmaf(a[abase + 2], inv, bp[2]);
  o0v.w = fmaf(a[abase + 3], inv, bp[3]);
  o1v.x = fmaf(a[abase + 4], inv, bp[4]);
  o1v.y = fmaf(a[abase + 5], inv, bp[5]);
  o1v.z = fmaf(a[abase + 6], inv, bp[6]);
  o1v.w = fmaf(a[abase + 7], inv, bp[7]);
  *(float4*)(op) = o0v;
  *(float4*)(op + 4) = o1v;
}

// ---------------- K6: BN column stats ----------------
__global__ __launch_bounds__(256) void bnstats_kernel(
    const float* __restrict__ h, float* __restrict__ sums,
    float* __restrict__ sumsq, int N)
{
  __shared__ float rs[256], rss[256];
  const int c = threadIdx.x & 127;
  const int half = threadIdx.x >> 7;
  const int rowsPer = (N + gridDim.x - 1) / gridDim.x;
  const int r0 = blockIdx.x * rowsPer;
  const int r1 = min(N, r0 + rowsPer);
  float s = 0.f, ss = 0.f;
  for (int r = r0 + half; r < r1; r += 2) {
    float v = h[(size_t)r * DD + c];
    s += v; ss += v * v;
  }
  rs[threadIdx.x] = s; rss[threadIdx.x] = ss;
  __syncthreads();
  if (threadIdx.x < 128) {
    s = rs[threadIdx.x] + rs[threadIdx.x + 128];
    ss = rss[threadIdx.x] + rss[threadIdx.x + 128];
    atomicAdd(&sums[c], s);
    atomicAdd(&sumsq[c], ss);
  }
}

// ---------------- K7: 4-wave hidden-split MLP (r18 epilogue, no fused stats) ----------------
__global__ __launch_bounds__(256, 2) void mlp_mfma_kernel(
    const float* __restrict__ hbuf, const float* __restrict__ sum1,
    const float* __restrict__ ss1, const float* __restrict__ bn1_g,
    const float* __restrict__ bn1_b, const _Float16* __restrict__ W1TP,
    const _Float16* __restrict__ W2P, const float* __restrict__ b1,
    const float* __restrict__ b2, float* __restrict__ out, int N)
{
  __shared__ char myA[8192];
  __shared__ char xch[3 * 8192];
  const int tid = threadIdx.x;
  const int wv = tid >> 6;
  const int lane = tid & 63;
  const int l15 = lane & 15, l4 = lane >> 4;
  const int n0 = blockIdx.x * 32;
  if (n0 >= N) return;

  {  // stage x-slice cooperatively: BN1-fused f16 swizzled
    const int c0 = (tid & 31) * 4;
    const int rq = tid >> 5;
    float sc[4], sh[4];
    #pragma unroll
    for (int jj = 0; jj < 4; ++jj) {
      float mean = sum1[c0 + jj] / (float)N;
      float var = ss1[c0 + jj] / (float)N - mean * mean;
      float s = bn1_g[c0 + jj] * rsqrtf(var + 1e-5f);
      sc[jj] = s; sh[jj] = bn1_b[c0 + jj] - mean * s;
    }
    #pragma unroll
    for (int it = 0; it < 4; ++it) {
      const int row = it * 8 + rq;
      const int n = n0 + row;
      float4 v = make_float4(0.f, 0.f, 0.f, 0.f);
      if (n < N) v = *(const float4*)(hbuf + (size_t)n * DD + c0);
      half4 hv;
      hv[0] = (_Float16)fmaf(v.x, sc[0], sh[0]);
      hv[1] = (_Float16)fmaf(v.y, sc[1], sh[1]);
      hv[2] = (_Float16)fmaf(v.z, sc[2], sh[2]);
      hv[3] = (_Float16)fmaf(v.w, sc[3], sh[3]);
      *(half4*)(myA + swz256(row, c0 * 2)) = hv;
    }
  }
  __syncthreads();

  half8 xf[2][4];
  #pragma unroll
  for (int nb = 0; nb < 2; ++nb)
    #pragma unroll
    for (int kc = 0; kc < 4; ++kc)
      xf[nb][kc] = *(const half8*)(myA + swz256(nb * 16 + l15, kc * 64 + l4 * 16));

  floatx4 acc2[2][8];
  #pragma unroll
  for (int nb = 0; nb < 2; ++nb)
    #pragma unroll
    for (int cb = 0; cb < 8; ++cb) acc2[nb][cb] = (floatx4)0.f;

  half8 a2s[4][2];
  #pragma unroll
  for (int c8 = 0; c8 < 4; ++c8) {
    const int c = wv * 4 + c8;
    floatx4 dA[2], dB[2];
    dA[0] = (floatx4)0.f; dA[1] = (floatx4)0.f;
    dB[0] = (floatx4)0.f; dB[1] = (floatx4)0.f;
    half8 wA[4], wB[4];
    #pragma unroll
    for (int kc = 0; kc < 4; ++kc) {
      wA[kc] = *(const half8*)(W1TP + (size_t)((2 * c) * 4 + kc) * 512 + (l4 * 16 + l15) * 8);
      wB[kc] = *(const half8*)(W1TP + (size_t)((2 * c + 1) * 4 + kc) * 512 + (l4 * 16 + l15) * 8);
    }
    __builtin_amdgcn_s_setprio(1);
    #pragma unroll
    for (int kc = 0; kc < 4; ++kc) {
      dA[0] = __builtin_amdgcn_mfma_f32_16x16x32_f16(wA[kc], xf[0][kc], dA[0], 0, 0, 0);
      dA[1] = __builtin_amdgcn_mfma_f32_16x16x32_f16(wA[kc], xf[1][kc], dA[1], 0, 0, 0);
      dB[0] = __builtin_amdgcn_mfma_f32_16x16x32_f16(wB[kc], xf[0][kc], dB[0], 0, 0, 0);
      dB[1] = __builtin_amdgcn_mfma_f32_16x16x32_f16(wB[kc], xf[1][kc], dB[1], 0, 0, 0);
    }
    __builtin_amdgcn_s_setprio(0);
    floatx4 bA = *(const floatx4*)&b1[(2 * c) * 16 + l4 * 4];
    floatx4 bB = *(const floatx4*)&b1[(2 * c + 1) * 16 + l4 * 4];
    #pragma unroll
    for (int nb = 0; nb < 2; ++nb) {
      #pragma unroll
      for (int r = 0; r < 4; ++r) {
        float vA = dA[nb][r] + bA[r];
        float vB = dB[nb][r] + bB[r];
        a2s[c8][nb][r]     = (_Float16)(vA > 0.f ? vA : 0.f);
        a2s[c8][nb][r + 4] = (_Float16)(vB > 0.f ? vB : 0.f);
      }
    }
  }
  #pragma unroll
  for (int c8 = 0; c8 < 4; ++c8) {
    const int c = wv * 4 + c8;
    half8 w2[8];
    #pragma unroll
    for (int cb = 0; cb < 8; ++cb)
      w2[cb] = *(const half8*)(W2P + (size_t)(c * 8 + cb) * 512 + (l4 * 16 + l15) * 8);
    __builtin_amdgcn_s_setprio(1);
    #pragma unroll
    for (int cb = 0; cb < 8; ++cb) {
      acc2[0][cb] = __builtin_amdgcn_mfma_f32_16x16x32_f16(a2s[c8][0], w2[cb], acc2[0][cb], 0, 0, 0);
      acc2[1][cb] = __builtin_amdgcn_mfma_f32_16x16x32_f16(a2s[c8][1], w2[cb], acc2[1][cb], 0, 0, 0);
    }
    __builtin_amdgcn_s_setprio(0);
  }

  if (wv != 0) {
    char* myX = xch + (wv - 1) * 8192;
    #pragma unroll
    for (int nb = 0; nb < 2; ++nb) {
      #pragma unroll
      for (int cb = 0; cb < 8; ++cb) {
        half4 hv;
        #pragma unroll
        for (int r = 0; r < 4; ++r) hv[r] = (_Float16)acc2[nb][cb][r];
        *(half4*)(myX + ((nb * 8 + cb) * 64 + lane) * 8) = hv;
      }
    }
  }
  __syncthreads();
  if (wv == 0) {
    float b2v[8];
    #pragma unroll
    for (int cb = 0; cb < 8; ++cb) b2v[cb] = b2[cb * 16 + l15];
    #pragma unroll
    for (int sw = 0; sw < 3; ++sw) {
      #pragma unroll
      for (int nb = 0; nb < 2; ++nb) {
        #pragma unroll
        for (int cb = 0; cb < 8; ++cb) {
          half4 hv = *(const half4*)(xch + sw * 8192 + ((nb * 8 + cb) * 64 + lane) * 8);
          #pragma unroll
          for (int r = 0; r < 4; ++r) acc2[nb][cb][r] += (float)hv[r];
        }
      }
    }
    #pragma unroll
    for (int nb = 0; nb < 2; ++nb) {
      #pragma unroll
      for (int r = 0; r < 4; ++r) {
        const int rown = n0 + nb * 16 + l4 * 4 + r;
        if (rown < N) {
          #pragma unroll
          for (int cb = 0; cb < 8; ++cb)
            out[(size_t)rown * DD + cb * 16 + l15] = acc2[nb][cb][r] + b2v[cb];
        }
      }
    }
  }
}

// ---------------- K8: BN2 finalize + apply in one pass ----------------
__global__ __launch_bounds__(256) void applybn_kernel(
    float* __restrict__ out, const float* __restrict__ sum2,
    const float* __restrict__ ss2, const float* __restrict__ gamma,
    const float* __restrict__ beta, int N, int total4)
{
  __shared__ float sc[128], sh[128];
  if (threadIdx.x < 128) {
    int c = threadIdx.x;
    float mean = sum2[c] / (float)N;
    float var = ss2[c] / (float)N - mean * mean;
    float s = gamma[c] * rsqrtf(var + 1e-5f);
    sc[c] = s;
    sh[c] = beta[c] - mean * s;
  }
  __syncthreads();
  int i = blockIdx.x * 256 + threadIdx.x;
  const int stride = gridDim.x * 256;
  for (; i < total4; i += stride) {
    float4 v = ((float4*)out)[i];
    int c = (i & 31) * 4;
    float4 scv = *(const float4*)&sc[c];
    float4 shv = *(const float4*)&sh[c];
    v.x = fmaf(v.x, scv.x, shv.x); v.y = fmaf(v.y, scv.y, shv.y);
    v.z = fmaf(v.z, scv.z, shv.z); v.w = fmaf(v.w, scv.w, shv.w);
    ((float4*)out)[i] = v;
  }
}

extern "C" void kernel_launch(void* const* d_in, const int* in_sizes, int n_in,
                              void* d_out, int out_size, void* d_ws, size_t ws_size,
                              hipStream_t stream) {
  const float* x        = (const float*)d_in[0];
  const int*   src      = (const int*)d_in[1];
  const int*   dst      = (const int*)d_in[2];
  const float* W        = (const float*)d_in[3];
  const float* attn_l   = (const float*)d_in[4];
  const float* attn_r   = (const float*)d_in[5];
  const float* bias_gat = (const float*)d_in[6];
  const float* bn1_g    = (const float*)d_in[7];
  const float* bn1_b    = (const float*)d_in[8];
  const float* W1       = (const float*)d_in[9];
  const float* b1       = (const float*)d_in[10];
  const float* W2       = (const float*)d_in[11];
  const float* b2       = (const float*)d_in[12];
  const float* bn2_g    = (const float*)d_in[13];
  const float* bn2_b    = (const float*)d_in[14];
  float* out = (float*)d_out;

  const int N = in_sizes[0] / DD;
  const int E = in_sizes[1];
  const int NPAD = ((N + 1023) / 1024) * 1024;
  const int NCHUNK = NPAD / 1024;
  const int T = (N + 31) / 32;
  const int countB = (E + 255) / 256;

  // workspace layout
  _Float16* feat16 = (_Float16*)d_ws;                 // N*128 f16 (padded to even)
  float* hbuf = (float*)(feat16 + (size_t)((N + 1) & ~1) * DD);  // N*128 f32
  float* el   = hbuf + (size_t)N * DD;                // N*8
  float* er   = el + (size_t)N * NHEAD;               // N*8
  int* counts = (int*)(er + (size_t)N * NHEAD);       // NPAD
  int* offsets = counts + NPAD;                       // NPAD
  int* srcl   = offsets + NPAD;                       // E
  int* btot   = srcl + E;                             // 64
  int* bof    = btot + 64;                            // 64
  float* stats = (float*)(bof + 64);                  // 1024 floats
  float* sum1 = stats, *ss1 = stats + 128;
  float* sum2 = stats + 256, *ss2 = stats + 384;
  _Float16* WP   = (_Float16*)(stats + 1024);         // 16384 f16
  _Float16* W1TP = WP + 4 * 128 * 32;                 // 65536 f16
  _Float16* W2P  = W1TP + 65536;                      // 65536 f16
  int* rank = (int*)hbuf;                             // E ints (hbuf dead until agg)

  hipMemsetAsync(counts, 0, (size_t)NPAD * sizeof(int), stream);
  hipMemsetAsync(stats, 0, 512 * sizeof(float), stream);

  pack_kernel<<<64, 256, 0, stream>>>(W, WP);
  featcount_kernel<<<NB + countB + 256, 256, 0, stream>>>(
      x, WP, attn_l, attn_r, feat16, el, er, N, T,
      dst, counts, rank, E, W1, W2, W1TP, W2P, countB);
  scan1_kernel<<<NCHUNK, 256, 0, stream>>>(counts, offsets, btot);
  scan2_kernel<<<1, 64, 0, stream>>>(btot, bof, NCHUNK);
  fill_kernel<<<countB, 256, 0, stream>>>(src, dst, offsets, bof, rank, srcl, E);
  agg_kernel<<<(N * 16 + 255) / 256, 256, 0, stream>>>(feat16, el, er, offsets, bof,
                                                       srcl, bias_gat, hbuf, N);
  bnstats_kernel<<<256, 256, 0, stream>>>(hbuf, sum1, ss1, N);
  mlp_mfma_kernel<<<T, 256, 0, stream>>>(hbuf, sum1, ss1, bn1_g, bn1_b, W1TP, W2P,
                                         b1, b2, out, N);
  bnstats_kernel<<<256, 256, 0, stream>>>(out, sum2, ss2, N);
  applybn_kernel<<<2048, 256, 0, stream>>>(out, sum2, ss2, bn2_g, bn2_b, N, N * DD / 4);
}

// Round 21
// 206.437 us; speedup vs baseline: 1.0288x; 1.0288x over previous
//
#include <hip/hip_runtime.h>
#include <math.h>

#define NHEAD 8
#define DD 128
#define HIDD 512
#define NB 768   // persistent feat blocks inside fused kernel A

typedef _Float16 half8 __attribute__((ext_vector_type(8)));
typedef _Float16 half4 __attribute__((ext_vector_type(4)));
typedef float floatx4 __attribute__((ext_vector_type(4)));

__device__ __forceinline__ int swz256(int row, int bytecol) {  // 256B rows (128 f16)
  return row * 256 + (bytecol ^ ((row & 15) << 4));
}

// ---------------- K0: pack WP only (needed immediately by featcount) ----------------
__global__ __launch_bounds__(256) void pack_kernel(
    const float* __restrict__ W, _Float16* __restrict__ WP)
{
  int i = blockIdx.x * 256 + threadIdx.x;
  if (i < 4 * 128 * 4 * 8) {   // WP <- W[128][128]
    int ii = i & 7, l4 = (i >> 3) & 3, col = (i >> 5) & 127, kc = i >> 12;
    WP[i] = (_Float16)W[(kc * 32 + l4 * 8 + ii) * DD + col];
  }
}

// ---------------- KA: fused feat+elr (persistent MFMA) | count | pack W1TP/W2P ----------------
// Blocks [0, NB): feat = f16(x @ W) + el/er epilogue.
// Blocks [NB, NB+countB): in-degree histogram + per-edge rank.
// Blocks [NB+countB, NB+countB+256): pack W1TP/W2P (read only by mlp, much later).
__global__ __launch_bounds__(256) void featcount_kernel(
    const float* __restrict__ x, const _Float16* __restrict__ WP,
    const float* __restrict__ attn_l, const float* __restrict__ attn_r,
    _Float16* __restrict__ feat16, float* __restrict__ el, float* __restrict__ er,
    int N, int T,
    const int* __restrict__ dst, int* __restrict__ counts,
    int* __restrict__ rank, int E,
    const float* __restrict__ W1, const float* __restrict__ W2,
    _Float16* __restrict__ W1TP, _Float16* __restrict__ W2P, int countB)
{
  if (blockIdx.x >= NB + countB) {   // ---- pack W1TP / W2P path ----
    int i = (blockIdx.x - NB - countB) * 256 + threadIdx.x;   // 0..65535
    {
      int ii = i & 7, e = (i >> 3) & 63, tile = i >> 9;
      int l4 = e >> 4, l15 = e & 15, hb = tile >> 2, kc = tile & 3;
      W1TP[i] = (_Float16)W1[(size_t)(kc * 32 + l4 * 8 + ii) * HIDD + hb * 16 + l15];
    }
    {
      int ii = i & 7, e = (i >> 3) & 63, tile = i >> 9;
      int l4 = e >> 4, l15 = e & 15, c = tile >> 3, cb = tile & 7;
      int hidden = (ii < 4) ? (2 * c) * 16 + 4 * l4 + ii
                            : (2 * c + 1) * 16 + 4 * l4 + (ii - 4);
      W2P[i] = (_Float16)W2[(size_t)hidden * DD + cb * 16 + l15];
    }
    return;
  }
  if (blockIdx.x >= NB) {   // ---- count path ----
    int e = (blockIdx.x - NB) * 256 + threadIdx.x;
    if (e < E) rank[e] = atomicAdd(&counts[dst[e]], 1);
    return;
  }
  // ---- feat path ----
  __shared__ char xs[32 * 256];   // 8KB f16 swizzled A-tile
  const int tid = threadIdx.x;
  const int wv = tid >> 6, lane = tid & 63;
  const int l15 = lane & 15, l4 = lane >> 4;
  const int row = tid >> 3, seg = tid & 7;

  const float al0 = attn_l[wv * 32 + l15], al1 = attn_l[wv * 32 + 16 + l15];
  const float ar0 = attn_r[wv * 32 + l15], ar1 = attn_r[wv * 32 + 16 + l15];

  int t = blockIdx.x;
  float4 pre[4];
  {
    const int n = t * 32 + row;
    const bool ok = (t < T) && (n < N);
    const float4* sp = (const float4*)(x + (size_t)n * DD + seg * 16);
    const float4 z = make_float4(0.f, 0.f, 0.f, 0.f);
    #pragma unroll
    for (int c = 0; c < 4; ++c) pre[c] = ok ? sp[c] : z;
  }

  for (; t < T; t += NB) {
    const int n0 = t * 32;
    {  // stage: convert f32->f16 once, 2x 16B swizzled stores
      half8 h0, h1;
      #pragma unroll
      for (int c = 0; c < 4; ++c) {
        float4 v = pre[c];
        if (c < 2) {
          h0[c * 4 + 0] = (_Float16)v.x; h0[c * 4 + 1] = (_Float16)v.y;
          h0[c * 4 + 2] = (_Float16)v.z; h0[c * 4 + 3] = (_Float16)v.w;
        } else {
          h1[(c - 2) * 4 + 0] = (_Float16)v.x; h1[(c - 2) * 4 + 1] = (_Float16)v.y;
          h1[(c - 2) * 4 + 2] = (_Float16)v.z; h1[(c - 2) * 4 + 3] = (_Float16)v.w;
        }
      }
      *(half8*)(xs + swz256(row, seg * 32)) = h0;
      *(half8*)(xs + swz256(row, seg * 32 + 16)) = h1;
    }
    __syncthreads();

    floatx4 acc[2][2];
    #pragma unroll
    for (int mf = 0; mf < 2; ++mf) { acc[mf][0] = (floatx4)0.f; acc[mf][1] = (floatx4)0.f; }

    #pragma unroll
    for (int kc = 0; kc < 4; ++kc) {
      half8 b0 = *(const half8*)(WP + ((kc * 128 + wv * 32 + l15) * 4 + l4) * 8);
      half8 b1 = *(const half8*)(WP + ((kc * 128 + wv * 32 + 16 + l15) * 4 + l4) * 8);
      #pragma unroll
      for (int mf = 0; mf < 2; ++mf) {
        half8 af = *(const half8*)(xs + swz256(mf * 16 + l15, kc * 64 + l4 * 16));
        acc[mf][0] = __builtin_amdgcn_mfma_f32_16x16x32_f16(af, b0, acc[mf][0], 0, 0, 0);
        acc[mf][1] = __builtin_amdgcn_mfma_f32_16x16x32_f16(af, b1, acc[mf][1], 0, 0, 0);
      }
    }

    {  // prefetch next tile
      const int tn = t + NB;
      const int n = tn * 32 + row;
      const bool ok = (tn < T) && (n < N);
      const float4* sp = (const float4*)(x + (size_t)n * DD + seg * 16);
      const float4 z = make_float4(0.f, 0.f, 0.f, 0.f);
      #pragma unroll
      for (int c = 0; c < 4; ++c) pre[c] = ok ? sp[c] : z;
    }

    // epilogue: store feat16 + el/er via 16-lane shfl reduction (VALU is free here)
    #pragma unroll
    for (int mf = 0; mf < 2; ++mf) {
      #pragma unroll
      for (int r = 0; r < 4; ++r) {
        const int rown = n0 + mf * 16 + l4 * 4 + r;
        float v0 = acc[mf][0][r], v1 = acc[mf][1][r];
        float e0l = v0 * al0, e0r = v0 * ar0;
        float e1l = v1 * al1, e1r = v1 * ar1;
        #pragma unroll
        for (int d = 1; d < 16; d <<= 1) {
          e0l += __shfl_xor(e0l, d, 64); e0r += __shfl_xor(e0r, d, 64);
          e1l += __shfl_xor(e1l, d, 64); e1r += __shfl_xor(e1r, d, 64);
        }
        if (rown < N) {
          feat16[(size_t)rown * DD + wv * 32 + l15] = (_Float16)v0;
          feat16[(size_t)rown * DD + wv * 32 + 16 + l15] = (_Float16)v1;
          if (l15 == 0) {
            el[rown * NHEAD + wv * 2] = e0l;     er[rown * NHEAD + wv * 2] = e0r;
            el[rown * NHEAD + wv * 2 + 1] = e1l; er[rown * NHEAD + wv * 2 + 1] = e1r;
          }
        }
      }
    }
    __syncthreads();
  }
}

// ---------------- K3a/K3b: two-level exclusive scan ----------------
__global__ __launch_bounds__(256) void scan1_kernel(const int* __restrict__ counts,
                                                    int* __restrict__ offsets,
                                                    int* __restrict__ btot)
{
  __shared__ int wsum[4];
  const int lane = threadIdx.x & 63;
  const int wid = threadIdx.x >> 6;
  int4 c = *(const int4*)(counts + blockIdx.x * 1024 + threadIdx.x * 4);
  int q = c.x + c.y + c.z + c.w;
  int incl = q;
  #pragma unroll
  for (int d = 1; d < 64; d <<= 1) {
    int t = __shfl_up(incl, d, 64);
    if (lane >= d) incl += t;
  }
  if (lane == 63) wsum[wid] = incl;
  __syncthreads();
  int wprefix = 0;
  for (int w = 0; w < wid; ++w) wprefix += wsum[w];
  int excl = wprefix + incl - q;
  int4 o;
  o.x = excl; o.y = excl + c.x; o.z = o.y + c.y; o.w = o.z + c.z;
  *(int4*)(offsets + blockIdx.x * 1024 + threadIdx.x * 4) = o;
  if (threadIdx.x == 0) btot[blockIdx.x] = wsum[0] + wsum[1] + wsum[2] + wsum[3];
}

__global__ __launch_bounds__(64) void scan2_kernel(const int* __restrict__ btot,
                                                   int* __restrict__ bof, int nchunk)
{
  const int t = threadIdx.x;
  const int K = (nchunk + 63) >> 6;
  const int base = t * K;
  int s = 0;
  for (int i = 0; i < K; ++i) if (base + i < nchunk) s += btot[base + i];
  int incl = s;
  #pragma unroll
  for (int d = 1; d < 64; d <<= 1) {
    int tt = __shfl_up(incl, d, 64);
    if (t >= d) incl += tt;
  }
  int run = incl - s;
  for (int i = 0; i < K; ++i) if (base + i < nchunk) { bof[base + i] = run; run += btot[base + i]; }
}

// ---------------- K4: bucket edges by dst (lightweight scatter only) ----------------
__global__ __launch_bounds__(256) void fill_kernel(const int* __restrict__ src,
                                                   const int* __restrict__ dst,
                                                   const int* __restrict__ offsets,
                                                   const int* __restrict__ bof,
                                                   const int* __restrict__ rank,
                                                   int* __restrict__ srcl, int E)
{
  int e = blockIdx.x * 256 + threadIdx.x;
  if (e < E) {
    int d = dst[e];
    srcl[offsets[d] + bof[d >> 10] + rank[e]] = src[e];
  }
}

// ---------------- K5: pair-split aggregate, fused el-gather, unroll x4 ----------------
__global__ __launch_bounds__(256) void agg_kernel(
    const _Float16* __restrict__ feat16, const float* __restrict__ el,
    const float* __restrict__ er, const int* __restrict__ offsets,
    const int* __restrict__ bof, const int* __restrict__ srcl,
    const float* __restrict__ bias, float* __restrict__ hout, int N)
{
  int gid = blockIdx.x * 256 + threadIdx.x;
  if (gid >= N * 16) return;
  const int n = gid >> 4;
  const int sub = gid & 15;
  const int hh = sub >> 1;
  const int half = sub & 1;
  const int o0 = offsets[n] + bof[n >> 10];
  const int o1 = offsets[n + 1] + bof[(n + 1) >> 10];
  const int cnt = o1 - o0;
  const int mid = o0 + ((cnt + 1) >> 1);
  int j = half ? mid : o0;
  const int je = half ? o1 : mid;
  const float er_nh = er[n * NHEAD + hh];

  float s = 0.f;
  float a[16];
  #pragma unroll
  for (int d = 0; d < 16; ++d) a[d] = 0.f;

  for (; j + 3 < je; j += 4) {
    const int s0 = srcl[j], s1 = srcl[j + 1], s2 = srcl[j + 2], s3 = srcl[j + 3];
    float e0 = el[s0 * NHEAD + hh] + er_nh;
    float e1 = el[s1 * NHEAD + hh] + er_nh;
    float e2 = el[s2 * NHEAD + hh] + er_nh;
    float e3 = el[s3 * NHEAD + hh] + er_nh;
    const half8* f0p = (const half8*)(feat16 + (size_t)s0 * DD + hh * 16);
    const half8* f1p = (const half8*)(feat16 + (size_t)s1 * DD + hh * 16);
    const half8* f2p = (const half8*)(feat16 + (size_t)s2 * DD + hh * 16);
    const half8* f3p = (const half8*)(feat16 + (size_t)s3 * DD + hh * 16);
    e0 = e0 > 0.f ? e0 : 0.2f * e0;
    e1 = e1 > 0.f ? e1 : 0.2f * e1;
    e2 = e2 > 0.f ? e2 : 0.2f * e2;
    e3 = e3 > 0.f ? e3 : 0.2f * e3;
    const float p0 = __expf(e0), p1 = __expf(e1), p2 = __expf(e2), p3 = __expf(e3);
    half8 f00 = f0p[0], f01 = f0p[1];
    half8 f10 = f1p[0], f11 = f1p[1];
    half8 f20 = f2p[0], f21 = f2p[1];
    half8 f30 = f3p[0], f31 = f3p[1];
    s += (p0 + p1) + (p2 + p3);
    #pragma unroll
    for (int d = 0; d < 8; ++d) {
      float t0 = fmaf(p0, (float)f00[d], fmaf(p1, (float)f10[d], a[d]));
      a[d] = fmaf(p2, (float)f20[d], fmaf(p3, (float)f30[d], t0));
      float t1 = fmaf(p0, (float)f01[d], fmaf(p1, (float)f11[d], a[d + 8]));
      a[d + 8] = fmaf(p2, (float)f21[d], fmaf(p3, (float)f31[d], t1));
    }
  }
  for (; j < je; ++j) {
    const int s0 = srcl[j];
    float e0 = el[s0 * NHEAD + hh] + er_nh;
    e0 = e0 > 0.f ? e0 : 0.2f * e0;
    const float p0 = __expf(e0);
    const half8* f0p = (const half8*)(feat16 + (size_t)s0 * DD + hh * 16);
    half8 f00 = f0p[0], f01 = f0p[1];
    s += p0;
    #pragma unroll
    for (int d = 0; d < 8; ++d) {
      a[d]     = fmaf(p0, (float)f00[d], a[d]);
      a[d + 8] = fmaf(p0, (float)f01[d], a[d + 8]);
    }
  }

  s += __shfl_xor(s, 1, 64);
  #pragma unroll
  for (int d = 0; d < 16; ++d) a[d] += __shfl_xor(a[d], 1, 64);

  const float inv = (cnt > 0) ? 1.f / s : 0.f;
  const int cbase = hh * 16 + half * 8;
  float* op = hout + (size_t)n * DD + cbase;
  const float* bp = bias + cbase;
  const int abase = half * 8;
  float4 o0v, o1v;
  o0v.x = fmaf(a[abase + 0], inv, bp[0]);
  o0v.y = fmaf(a[abase + 1], inv, bp[1]);
  o0v.z = fmaf(a[abase + 2], inv, bp[2]);
  o0v.w = fmaf(a[abase + 3], inv, bp[3]);
  o1v.x = fmaf(a[abase + 4], inv, bp[4]);
  o1v.y = fmaf(a[abase + 5], inv, bp[5]);
  o1v.z = fmaf(a[abase + 6], inv, bp[6]);
  o1v.w = fmaf(a[abase + 7], inv, bp[7]);
  *(float4*)(op) = o0v;
  *(float4*)(op + 4) = o1v;
}

// ---------------- K6: BN column stats (BN1 on hbuf) ----------------
__global__ __launch_bounds__(256) void bnstats_kernel(
    const float* __restrict__ h, float* __restrict__ sums,
    float* __restrict__ sumsq, int N)
{
  __shared__ float rs[256], rss[256];
  const int c = threadIdx.x & 127;
  const int half = threadIdx.x >> 7;
  const int rowsPer = (N + gridDim.x - 1) / gridDim.x;
  const int r0 = blockIdx.x * rowsPer;
  const int r1 = min(N, r0 + rowsPer);
  float s = 0.f, ss = 0.f;
  for (int r = r0 + half; r < r1; r += 2) {
    float v = h[(size_t)r * DD + c];
    s += v; ss += v * v;
  }
  rs[threadIdx.x] = s; rss[threadIdx.x] = ss;
  __syncthreads();
  if (threadIdx.x < 128) {
    s = rs[threadIdx.x] + rs[threadIdx.x + 128];
    ss = rss[threadIdx.x] + rss[threadIdx.x + 128];
    atomicAdd(&sums[c], s);
    atomicAdd(&sumsq[c], ss);
  }
}

// ---------------- K7: 4-wave hidden-split MLP + fused BN2 stats ----------------
__global__ __launch_bounds__(256, 2) void mlp_mfma_kernel(
    const float* __restrict__ hbuf, const float* __restrict__ sum1,
    const float* __restrict__ ss1, const float* __restrict__ bn1_g,
    const float* __restrict__ bn1_b, const _Float16* __restrict__ W1TP,
    const _Float16* __restrict__ W2P, const float* __restrict__ b1,
    const float* __restrict__ b2, float* __restrict__ out,
    float* __restrict__ sums2, float* __restrict__ sumsq2, int N)
{
  __shared__ char myA[8192];
  __shared__ char xch[3 * 8192];
  const int tid = threadIdx.x;
  const int wv = tid >> 6;
  const int lane = tid & 63;
  const int l15 = lane & 15, l4 = lane >> 4;
  const int n0 = blockIdx.x * 32;
  if (n0 >= N) return;

  {  // stage x-slice cooperatively: BN1-fused f16 swizzled
    const int c0 = (tid & 31) * 4;
    const int rq = tid >> 5;
    float sc[4], sh[4];
    #pragma unroll
    for (int jj = 0; jj < 4; ++jj) {
      float mean = sum1[c0 + jj] / (float)N;
      float var = ss1[c0 + jj] / (float)N - mean * mean;
      float s = bn1_g[c0 + jj] * rsqrtf(var + 1e-5f);
      sc[jj] = s; sh[jj] = bn1_b[c0 + jj] - mean * s;
    }
    #pragma unroll
    for (int it = 0; it < 4; ++it) {
      const int row = it * 8 + rq;
      const int n = n0 + row;
      float4 v = make_float4(0.f, 0.f, 0.f, 0.f);
      if (n < N) v = *(const float4*)(hbuf + (size_t)n * DD + c0);
      half4 hv;
      hv[0] = (_Float16)fmaf(v.x, sc[0], sh[0]);
      hv[1] = (_Float16)fmaf(v.y, sc[1], sh[1]);
      hv[2] = (_Float16)fmaf(v.z, sc[2], sh[2]);
      hv[3] = (_Float16)fmaf(v.w, sc[3], sh[3]);
      *(half4*)(myA + swz256(row, c0 * 2)) = hv;
    }
  }
  __syncthreads();

  half8 xf[2][4];
  #pragma unroll
  for (int nb = 0; nb < 2; ++nb)
    #pragma unroll
    for (int kc = 0; kc < 4; ++kc)
      xf[nb][kc] = *(const half8*)(myA + swz256(nb * 16 + l15, kc * 64 + l4 * 16));

  floatx4 acc2[2][8];
  #pragma unroll
  for (int nb = 0; nb < 2; ++nb)
    #pragma unroll
    for (int cb = 0; cb < 8; ++cb) acc2[nb][cb] = (floatx4)0.f;

  half8 a2s[4][2];
  #pragma unroll
  for (int c8 = 0; c8 < 4; ++c8) {
    const int c = wv * 4 + c8;
    floatx4 dA[2], dB[2];
    dA[0] = (floatx4)0.f; dA[1] = (floatx4)0.f;
    dB[0] = (floatx4)0.f; dB[1] = (floatx4)0.f;
    half8 wA[4], wB[4];
    #pragma unroll
    for (int kc = 0; kc < 4; ++kc) {
      wA[kc] = *(const half8*)(W1TP + (size_t)((2 * c) * 4 + kc) * 512 + (l4 * 16 + l15) * 8);
      wB[kc] = *(const half8*)(W1TP + (size_t)((2 * c + 1) * 4 + kc) * 512 + (l4 * 16 + l15) * 8);
    }
    __builtin_amdgcn_s_setprio(1);
    #pragma unroll
    for (int kc = 0; kc < 4; ++kc) {
      dA[0] = __builtin_amdgcn_mfma_f32_16x16x32_f16(wA[kc], xf[0][kc], dA[0], 0, 0, 0);
      dA[1] = __builtin_amdgcn_mfma_f32_16x16x32_f16(wA[kc], xf[1][kc], dA[1], 0, 0, 0);
      dB[0] = __builtin_amdgcn_mfma_f32_16x16x32_f16(wB[kc], xf[0][kc], dB[0], 0, 0, 0);
      dB[1] = __builtin_amdgcn_mfma_f32_16x16x32_f16(wB[kc], xf[1][kc], dB[1], 0, 0, 0);
    }
    __builtin_amdgcn_s_setprio(0);
    floatx4 bA = *(const floatx4*)&b1[(2 * c) * 16 + l4 * 4];
    floatx4 bB = *(const floatx4*)&b1[(2 * c + 1) * 16 + l4 * 4];
    #pragma unroll
    for (int nb = 0; nb < 2; ++nb) {
      #pragma unroll
      for (int r = 0; r < 4; ++r) {
        float vA = dA[nb][r] + bA[r];
        float vB = dB[nb][r] + bB[r];
        a2s[c8][nb][r]     = (_Float16)(vA > 0.f ? vA : 0.f);
        a2s[c8][nb][r + 4] = (_Float16)(vB > 0.f ? vB : 0.f);
      }
    }
  }
  #pragma unroll
  for (int c8 = 0; c8 < 4; ++c8) {
    const int c = wv * 4 + c8;
    half8 w2[8];
    #pragma unroll
    for (int cb = 0; cb < 8; ++cb)
      w2[cb] = *(const half8*)(W2P + (size_t)(c * 8 + cb) * 512 + (l4 * 16 + l15) * 8);
    __builtin_amdgcn_s_setprio(1);
    #pragma unroll
    for (int cb = 0; cb < 8; ++cb) {
      acc2[0][cb] = __builtin_amdgcn_mfma_f32_16x16x32_f16(a2s[c8][0], w2[cb], acc2[0][cb], 0, 0, 0);
      acc2[1][cb] = __builtin_amdgcn_mfma_f32_16x16x32_f16(a2s[c8][1], w2[cb], acc2[1][cb], 0, 0, 0);
    }
    __builtin_amdgcn_s_setprio(0);
  }

  if (wv != 0) {
    char* myX = xch + (wv - 1) * 8192;
    #pragma unroll
    for (int nb = 0; nb < 2; ++nb) {
      #pragma unroll
      for (int cb = 0; cb < 8; ++cb) {
        half4 hv;
        #pragma unroll
        for (int r = 0; r < 4; ++r) hv[r] = (_Float16)acc2[nb][cb][r];
        *(half4*)(myX + ((nb * 8 + cb) * 64 + lane) * 8) = hv;
      }
    }
  }
  __syncthreads();
  if (wv == 0) {
    float b2v[8];
    #pragma unroll
    for (int cb = 0; cb < 8; ++cb) b2v[cb] = b2[cb * 16 + l15];
    #pragma unroll
    for (int sw = 0; sw < 3; ++sw) {
      #pragma unroll
      for (int nb = 0; nb < 2; ++nb) {
        #pragma unroll
        for (int cb = 0; cb < 8; ++cb) {
          half4 hv = *(const half4*)(xch + sw * 8192 + ((nb * 8 + cb) * 64 + lane) * 8);
          #pragma unroll
          for (int r = 0; r < 4; ++r) acc2[nb][cb][r] += (float)hv[r];
        }
      }
    }
    float scol[8], sqcol[8];
    #pragma unroll
    for (int cb = 0; cb < 8; ++cb) { scol[cb] = 0.f; sqcol[cb] = 0.f; }
    #pragma unroll
    for (int nb = 0; nb < 2; ++nb) {
      #pragma unroll
      for (int r = 0; r < 4; ++r) {
        const int rown = n0 + nb * 16 + l4 * 4 + r;
        const bool ok = rown < N;
        #pragma unroll
        for (int cb = 0; cb < 8; ++cb) {
          float v = ok ? (acc2[nb][cb][r] + b2v[cb]) : 0.f;
          if (ok) out[(size_t)rown * DD + cb * 16 + l15] = v;
          scol[cb] += v;
          sqcol[cb] += v * v;
        }
      }
    }
    // reduce over l4 (lanes stride 16), then 16 lanes issue BN2 stat atomics
    #pragma unroll
    for (int cb = 0; cb < 8; ++cb) {
      scol[cb] += __shfl_xor(scol[cb], 16, 64);
      scol[cb] += __shfl_xor(scol[cb], 32, 64);
      sqcol[cb] += __shfl_xor(sqcol[cb], 16, 64);
      sqcol[cb] += __shfl_xor(sqcol[cb], 32, 64);
    }
    if (l4 == 0) {
      #pragma unroll
      for (int cb = 0; cb < 8; ++cb) {
        atomicAdd(&sums2[cb * 16 + l15], scol[cb]);
        atomicAdd(&sumsq2[cb * 16 + l15], sqcol[cb]);
      }
    }
  }
}

// ---------------- K8: BN2 finalize + apply in one pass ----------------
__global__ __launch_bounds__(256) void applybn_kernel(
    float* __restrict__ out, const float* __restrict__ sum2,
    const float* __restrict__ ss2, const float* __restrict__ gamma,
    const float* __restrict__ beta, int N, int total4)
{
  __shared__ float sc[128], sh[128];
  if (threadIdx.x < 128) {
    int c = threadIdx.x;
    float mean = sum2[c] / (float)N;
    float var = ss2[c] / (float)N - mean * mean;
    float s = gamma[c] * rsqrtf(var + 1e-5f);
    sc[c] = s;
    sh[c] = beta[c] - mean * s;
  }
  __syncthreads();
  int i = blockIdx.x * 256 + threadIdx.x;
  const int stride = gridDim.x * 256;
  for (; i < total4; i += stride) {
    float4 v = ((float4*)out)[i];
    int c = (i & 31) * 4;
    float4 scv = *(const float4*)&sc[c];
    float4 shv = *(const float4*)&sh[c];
    v.x = fmaf(v.x, scv.x, shv.x); v.y = fmaf(v.y, scv.y, shv.y);
    v.z = fmaf(v.z, scv.z, shv.z); v.w = fmaf(v.w, scv.w, shv.w);
    ((float4*)out)[i] = v;
  }
}

extern "C" void kernel_launch(void* const* d_in, const int* in_sizes, int n_in,
                              void* d_out, int out_size, void* d_ws, size_t ws_size,
                              hipStream_t stream) {
  const float* x        = (const float*)d_in[0];
  const int*   src      = (const int*)d_in[1];
  const int*   dst      = (const int*)d_in[2];
  const float* W        = (const float*)d_in[3];
  const float* attn_l   = (const float*)d_in[4];
  const float* attn_r   = (const float*)d_in[5];
  const float* bias_gat = (const float*)d_in[6];
  const float* bn1_g    = (const float*)d_in[7];
  const float* bn1_b    = (const float*)d_in[8];
  const float* W1       = (const float*)d_in[9];
  const float* b1       = (const float*)d_in[10];
  const float* W2       = (const float*)d_in[11];
  const float* b2       = (const float*)d_in[12];
  const float* bn2_g    = (const float*)d_in[13];
  const float* bn2_b    = (const float*)d_in[14];
  float* out = (float*)d_out;

  const int N = in_sizes[0] / DD;
  const int E = in_sizes[1];
  const int NPAD = ((N + 1023) / 1024) * 1024;
  const int NCHUNK = NPAD / 1024;
  const int T = (N + 31) / 32;
  const int countB = (E + 255) / 256;

  // workspace layout
  _Float16* feat16 = (_Float16*)d_ws;                 // N*128 f16 (padded to even)
  float* hbuf = (float*)(feat16 + (size_t)((N + 1) & ~1) * DD);  // N*128 f32
  float* el   = hbuf + (size_t)N * DD;                // N*8
  float* er   = el + (size_t)N * NHEAD;               // N*8
  int* counts = (int*)(er + (size_t)N * NHEAD);       // NPAD
  int* offsets = counts + NPAD;                       // NPAD
  int* srcl   = offsets + NPAD;                       // E
  int* btot   = srcl + E;                             // 64
  int* bof    = btot + 64;                            // 64
  float* stats = (float*)(bof + 64);                  // 1024 floats
  float* sum1 = stats, *ss1 = stats + 128;
  float* sum2 = stats + 256, *ss2 = stats + 384;
  _Float16* WP   = (_Float16*)(stats + 1024);         // 16384 f16
  _Float16* W1TP = WP + 4 * 128 * 32;                 // 65536 f16
  _Float16* W2P  = W1TP + 65536;                      // 65536 f16
  int* rank = (int*)hbuf;                             // E ints (hbuf dead until agg)

  hipMemsetAsync(counts, 0, (size_t)NPAD * sizeof(int), stream);
  hipMemsetAsync(stats, 0, 512 * sizeof(float), stream);

  pack_kernel<<<64, 256, 0, stream>>>(W, WP);
  featcount_kernel<<<NB + countB + 256, 256, 0, stream>>>(
      x, WP, attn_l, attn_r, feat16, el, er, N, T,
      dst, counts, rank, E, W1, W2, W1TP, W2P, countB);
  scan1_kernel<<<NCHUNK, 256, 0, stream>>>(counts, offsets, btot);
  scan2_kernel<<<1, 64, 0, stream>>>(btot, bof, NCHUNK);
  fill_kernel<<<countB, 256, 0, stream>>>(src, dst, offsets, bof, rank, srcl, E);
  agg_kernel<<<(N * 16 + 255) / 256, 256, 0, stream>>>(feat16, el, er, offsets, bof,
                                                       srcl, bias_gat, hbuf, N);
  bnstats_kernel<<<256, 256, 0, stream>>>(hbuf, sum1, ss1, N);
  mlp_mfma_kernel<<<T, 256, 0, stream>>>(hbuf, sum1, ss1, bn1_g, bn1_b, W1TP, W2P,
                                         b1, b2, out, sum2, ss2, N);
  applybn_kernel<<<2048, 256, 0, stream>>>(out, sum2, ss2, bn2_g, bn2_b, N, N * DD / 4);
}